// Round 12
// baseline (277.419 us; speedup 1.0000x reference)
//
#include <hip/hip_runtime.h>
#include <cstdint>
#include <cstddef>
#include <type_traits>

static constexpr int NN   = 20000;     // nodes
static constexpr int MPAD = 20096;     // 157 * 128
static constexpr int ERAW = 320000;    // given edges
static constexpr int ETOT = ERAW + NN; // + self loops

typedef __attribute__((ext_vector_type(8))) short bf16x8;
typedef __attribute__((ext_vector_type(8))) unsigned short u16x8;
typedef __attribute__((ext_vector_type(4))) float f32x4;

__device__ __forceinline__ unsigned short f2bf(float f) {
  union { float f; unsigned u; } v; v.f = f;
  unsigned r = v.u + 0x7fffu + ((v.u >> 16) & 1u);
  return (unsigned short)(r >> 16);
}
__device__ __forceinline__ float bf2f(unsigned short u) {
  union { unsigned u; float f; } v; v.u = ((unsigned)u) << 16;
  return v.f;
}

__device__ __forceinline__ void gload_lds16(const void* g, void* l) {
  __builtin_amdgcn_global_load_lds(
      (const __attribute__((address_space(1))) unsigned int*)g,
      (__attribute__((address_space(3))) unsigned int*)l, 16, 0, 0);
}

// ---------------- x fp32 -> bf16 cast + zero-init (fused) ---------------------
__global__ __launch_bounds__(256) void cast_x_kernel(
    const float* __restrict__ x, unsigned short* __restrict__ xb,
    int* __restrict__ degp, float* __restrict__ stats, float* __restrict__ beff1) {
  int i8 = blockIdx.x * 256 + threadIdx.x;   // 8-elem chunk; 96 chunks/row
  if (i8 < NN) degp[i8] = 0;
  if (i8 < 1024) { stats[i8] = 0.f; beff1[i8] = 0.f; }
  size_t base = (size_t)i8 * 8;
  int row = i8 / 96;
  u16x8 o;
  if (row < NN) {
    float4 a = *(const float4*)&x[base];
    float4 b = *(const float4*)&x[base + 4];
    o[0] = f2bf(a.x); o[1] = f2bf(a.y); o[2] = f2bf(a.z); o[3] = f2bf(a.w);
    o[4] = f2bf(b.x); o[5] = f2bf(b.y); o[6] = f2bf(b.z); o[7] = f2bf(b.w);
  } else {
#pragma unroll
    for (int j = 0; j < 8; j++) o[j] = 0;
  }
  *(u16x8*)&xb[base] = o;
}

// ---------------- conv folded into W1: Weff^T[c][k*32+t], beff1[c] ------------
// grid (32 t, 8 c-chunks); thread pair (c, half) splits the o-loop 32/32.
__global__ __launch_bounds__(256) void weff_kernel(
    const float* __restrict__ conv_w, const float* __restrict__ conv_b,
    const float* __restrict__ W1l, const float* __restrict__ b1l,
    const float* __restrict__ W1r, const float* __restrict__ b1r,
    unsigned short* __restrict__ wc1, float* __restrict__ beff1) {
  __shared__ float ws[64 * 24];
  int t = blockIdx.x;                 // 0..31
  int tid = threadIdx.x;
  for (int i = tid; i < 64 * 24; i += 256) ws[i] = conv_w[i];
  __syncthreads();
  int c = blockIdx.y * 128 + (tid >> 1);   // 0..1023
  int half = tid & 1;
  const float* W; const float* bb; int cl;
  if (c < 512) { W = W1l; bb = b1l; cl = c; } else { W = W1r; bb = b1r; cl = c - 512; }
  float acc[24];
#pragma unroll
  for (int k = 0; k < 24; k++) acc[k] = 0.f;
  float bacc = (t == 0 && half == 0) ? bb[cl] : 0.f;
  for (int o = half * 32; o < half * 32 + 32; o += 4) {
    float Wv[4];
#pragma unroll
    for (int j = 0; j < 4; j++) Wv[j] = W[(size_t)((o + j) * 32 + t) * 512 + cl];
#pragma unroll
    for (int j = 0; j < 4; j++) {
      bacc += conv_b[o + j] * Wv[j];
#pragma unroll
      for (int k = 0; k < 24; k++) acc[k] += ws[(o + j) * 24 + k] * Wv[j];
    }
  }
#pragma unroll
  for (int k = 0; k < 24; k++) acc[k] += __shfl_xor(acc[k], 1);
  bacc += __shfl_xor(bacc, 1);
  if (half == 0) {
#pragma unroll
    for (int k = 0; k < 24; k++) wc1[(size_t)c * 768 + k * 32 + t] = f2bf(acc[k]);
    atomicAdd(&beff1[c], bacc);
  }
}

// ---------------- BN folded into W2 (parallel; sc/sh computed inline) ---------
__global__ __launch_bounds__(256) void w2fold_kernel(
    const float* __restrict__ stats, const float* __restrict__ gamma,
    const float* __restrict__ beta,
    const float* __restrict__ W2l, const float* __restrict__ b2l,
    const float* __restrict__ W2r, const float* __restrict__ b2r,
    unsigned short* __restrict__ wc2, float* __restrict__ beff2) {
  int c = blockIdx.x;                 // 0..255
  const float* W; const float* bb; int cl;
  if (c < 128) { W = W2l; bb = b2l; cl = c; } else { W = W2r; bb = b2r; cl = c - 128; }
  int tid = threadIdx.x, lane = tid & 63, wid = tid >> 6;
  float part = 0.f;
#pragma unroll
  for (int j = 0; j < 2; j++) {
    int k = tid * 2 + j;
    float mean = stats[k] * (1.f / NN);
    float var = stats[512 + k] * (1.f / NN) - mean * mean;
    float rstd = rsqrtf(var + 1e-5f);
    float sc = gamma[k] * rstd;
    float sh = beta[k] - sc * mean;
    float wv = W[(size_t)k * 128 + cl];
    wc2[(size_t)c * 512 + k] = f2bf(sc * wv);
    part += sh * wv;
  }
#pragma unroll
  for (int d = 32; d; d >>= 1) part += __shfl_xor(part, d);
  __shared__ float wsum[4];
  if (lane == 0) wsum[wid] = part;
  __syncthreads();
  if (tid == 0) beff2[c] = bb[cl] + wsum[0] + wsum[1] + wsum[2] + wsum[3];
}

// ---------------- bf16 MFMA GEMM (m97 2-phase + T2 swizzle + T1) --------------
template <typename OutT>
__global__ __launch_bounds__(256, 5) void gemm_kernel(
    const unsigned short* __restrict__ A, const unsigned short* __restrict__ B,
    const float* __restrict__ bias0, const float* __restrict__ bias1,
    OutT* __restrict__ C0, OutT* __restrict__ C1,
    int M, int K, int NT, int nsplit, int swz) {
  __shared__ __align__(16) unsigned short As[128 * 64];
  __shared__ __align__(16) unsigned short Bs[128 * 64];
  int bid = blockIdx.x;
  if (swz) bid = (bid & 7) * (gridDim.x >> 3) + (bid >> 3);  // XCD-chunked (nwg%8==0)
  int tm = bid / NT, tn = bid % NT;
  int tid = threadIdx.x, wid = tid >> 6, lane = tid & 63;
  int wr = wid >> 1, wc = wid & 1;
  const unsigned short* gA = A + (size_t)(tm * 128) * K;
  const unsigned short* gB = B + (size_t)(tn * 128) * K;
  int srow = wid * 8 + (lane >> 3);
  int scol = ((lane & 7) ^ (lane >> 3)) * 8;   // T2: srow&7 == lane>>3

  f32x4 acc[4][4];
  f32x4 zero = {0.f, 0.f, 0.f, 0.f};
#pragma unroll
  for (int i = 0; i < 4; i++)
#pragma unroll
    for (int j = 0; j < 4; j++) acc[i][j] = zero;

  int KT = K >> 6;
  for (int kt = 0; kt < KT; ++kt) {
    if (kt) __syncthreads();
    {
      const unsigned short* a0 = gA + (size_t)srow * K + kt * 64 + scol;
      const unsigned short* b0 = gB + (size_t)srow * K + kt * 64 + scol;
#pragma unroll
      for (int i = 0; i < 4; i++)
        gload_lds16(a0 + (size_t)i * 32 * K, &As[i * 2048 + wid * 512]);
#pragma unroll
      for (int i = 0; i < 4; i++)
        gload_lds16(b0 + (size_t)i * 32 * K, &Bs[i * 2048 + wid * 512]);
    }
    asm volatile("s_waitcnt vmcnt(0)" ::: "memory");
    __syncthreads();
#pragma unroll
    for (int kk = 0; kk < 2; kk++) {
      int ko = kk * 32 + (lane >> 4) * 8;
      int kosw = ko ^ ((lane & 7) << 3);       // T2 read: r&7 == lane&7
      bf16x8 af[4], bfr[4];
#pragma unroll
      for (int mi = 0; mi < 4; mi++)
        af[mi] = *(const bf16x8*)&As[(wr * 64 + mi * 16 + (lane & 15)) * 64 + kosw];
#pragma unroll
      for (int ni = 0; ni < 4; ni++)
        bfr[ni] = *(const bf16x8*)&Bs[(wc * 64 + ni * 16 + (lane & 15)) * 64 + kosw];
#pragma unroll
      for (int mi = 0; mi < 4; mi++)
#pragma unroll
        for (int ni = 0; ni < 4; ni++)
          acc[mi][ni] = __builtin_amdgcn_mfma_f32_16x16x32_bf16(
              af[mi], bfr[ni], acc[mi][ni], 0, 0, 0);
    }
  }

  int ncol_tile = tn * 128;
  OutT* Cd; const float* bs; int col0;
  if (ncol_tile < nsplit) { Cd = C0; bs = bias0; col0 = ncol_tile; }
  else { Cd = C1; bs = bias1; col0 = ncol_tile - nsplit; }
#pragma unroll
  for (int mi = 0; mi < 4; mi++) {
    int rbase = tm * 128 + wr * 64 + mi * 16 + (lane >> 4) * 4;
#pragma unroll
    for (int ni = 0; ni < 4; ni++) {
      int c = col0 + wc * 64 + ni * 16 + (lane & 15);
      float bv = bs[c];
#pragma unroll
      for (int j = 0; j < 4; j++) {
        int r = rbase + j;
        if (r < M) {
          float v = acc[mi][ni][j] + bv;
          if constexpr (sizeof(OutT) == 2) Cd[(size_t)r * nsplit + c] = f2bf(v);
          else Cd[(size_t)r * nsplit + c] = v;
        }
      }
    }
  }
}

// ---------------- CSR build (self-loop placed first per segment) --------------
__global__ void hist_kernel(const int* __restrict__ dst, int* deg, int E) {
  int e = blockIdx.x * 256 + threadIdx.x;
  if (e < E) atomicAdd(&deg[dst[e]], 1);
}
__global__ __launch_bounds__(1024) void scan1_kernel(
    const int* __restrict__ deg, int* __restrict__ off, int* __restrict__ btot, int n) {
  __shared__ int wsum[16];
  int tid = threadIdx.x, lane = tid & 63, w = tid >> 6;
  int i = blockIdx.x * 1024 + tid;
  int v = (i < n) ? deg[i] + 1 : 0;    // +1 self loop
  int s = v;
#pragma unroll
  for (int d = 1; d < 64; d <<= 1) {
    int t = __shfl_up(s, d);
    if (lane >= d) s += t;
  }
  if (lane == 63) wsum[w] = s;
  __syncthreads();
  if (w == 0 && lane < 16) {
    int t = wsum[lane];
#pragma unroll
    for (int d = 1; d < 16; d <<= 1) {
      int u = __shfl_up(t, d);
      if (lane >= d) t += u;
    }
    wsum[lane] = t;
  }
  __syncthreads();
  int incl = (w ? wsum[w - 1] : 0) + s;
  if (i < n) off[i] = incl - v;               // block-local exclusive
  if (tid == 1023) btot[blockIdx.x] = incl;
}
__global__ void scan2_kernel(const int* __restrict__ btot, int* __restrict__ gbase,
                             int* __restrict__ off, int nb, int n) {
  int lane = threadIdx.x;
  int v = lane < nb ? btot[lane] : 0;
  int s = v;
#pragma unroll
  for (int d = 1; d < 64; d <<= 1) {
    int t = __shfl_up(s, d);
    if (lane >= d) s += t;
  }
  if (lane < nb) gbase[lane] = s - v;
  if (lane == nb - 1) off[n] = s;
}
__global__ __launch_bounds__(1024) void scan3_kernel(
    int* __restrict__ off, int* __restrict__ cursor,
    const int* __restrict__ gbase, int* __restrict__ esrc, int n) {
  int i = blockIdx.x * 1024 + threadIdx.x;
  if (i < n) {
    int v = off[i] + gbase[blockIdx.x];
    off[i] = v;
    cursor[i] = v + 1;    // slot v reserved for self loop
    esrc[v] = i;
  }
}
__global__ void scatter_kernel(const int* __restrict__ src, const int* __restrict__ dst,
                               int* cursor, int* __restrict__ esrc, int E) {
  int e = blockIdx.x * 256 + threadIdx.x;
  if (e < E) {
    int pos = atomicAdd(&cursor[dst[e]], 1);
    esrc[pos] = src[e];
  }
}

// ---------------- GATv2 aggregate: per-wave grid-stride over nodes ------------
// 1024 blocks fully resident (VGPR 60, no LDS): no command-processor refill.
// Waves never synchronize; each wave walks nodes {gw, gw+NW, ...} independently.
// Pad nodes (>= n) write zero rows (GEMM2 A pad). Inner loop identical to r11.
template <int VPL, typename OutT>
__global__ __launch_bounds__(256) void gat_agg_kernel(
    const unsigned short* __restrict__ xl, const unsigned short* __restrict__ xr,
    const float* __restrict__ att, const float* __restrict__ bias,
    const int* __restrict__ off, const int* __restrict__ esrc,
    OutT* __restrict__ out, int npad, int n, int do_relu) {
  constexpr int C = VPL * 64;
  using RawT = std::conditional_t<VPL == 8, uint4, unsigned int>;
  int lane = threadIdx.x & 63;
  int base = lane * VPL;
  float attv[VPL];
#pragma unroll
  for (int v = 0; v < VPL; v++) attv[v] = att[base + v];
  float xrv[VPL];
  auto cvt = [](RawT r, float* xv) {
    if constexpr (VPL == 8) {
      unsigned u[4] = {r.x, r.y, r.z, r.w};
#pragma unroll
      for (int i = 0; i < 4; i++) {
        xv[2 * i]     = __uint_as_float(u[i] << 16);
        xv[2 * i + 1] = __uint_as_float(u[i] & 0xffff0000u);
      }
    } else {
      xv[0] = __uint_as_float(r << 16);
      xv[1] = __uint_as_float(r & 0xffff0000u);
    }
  };
  auto score = [&](const float* xv) {
    float p = 0.f;
#pragma unroll
    for (int v = 0; v < VPL; v++) {
      float t = xv[v] + xrv[v];
      p += attv[v] * fmaxf(t, 0.2f * t);   // leaky_relu(0.2) = max(t, 0.2t)
    }
    return p;
  };
  int NW = gridDim.x * 4;                 // total waves
  for (int node = blockIdx.x * 4 + (threadIdx.x >> 6); node < npad; node += NW) {
    if (node >= n) {
#pragma unroll
      for (int v = 0; v < VPL; v++) out[(size_t)node * C + base + v] = OutT(0);
      continue;
    }
#pragma unroll
    for (int v = 0; v < VPL; v++) xrv[v] = bf2f(xr[(size_t)node * C + base + v]);
    float s0 = 0.f, s1 = 0.f;
    float acc0[VPL], acc1[VPL];
#pragma unroll
    for (int v = 0; v < VPL; v++) { acc0[v] = 0.f; acc1[v] = 0.f; }
    int e0 = off[node], e1 = off[node + 1];
    int e = e0;
    for (; e + 3 < e1; e += 4) {
      int s0i = esrc[e], s1i = esrc[e + 1], s2i = esrc[e + 2], s3i = esrc[e + 3];
      RawT r0 = *(const RawT*)(xl + (size_t)s0i * C + base);
      RawT r1 = *(const RawT*)(xl + (size_t)s1i * C + base);
      RawT r2 = *(const RawT*)(xl + (size_t)s2i * C + base);
      RawT r3 = *(const RawT*)(xl + (size_t)s3i * C + base);
      float x0[VPL], x1[VPL], x2[VPL], x3[VPL];
      cvt(r0, x0); cvt(r1, x1); cvt(r2, x2); cvt(r3, x3);
      float p0 = score(x0), p1 = score(x1), p2 = score(x2), p3 = score(x3);
      // packed 4-value butterfly: one tree instead of four.
      p0 += __shfl_xor(p0, 32); p1 += __shfl_xor(p1, 32);
      p2 += __shfl_xor(p2, 32); p3 += __shfl_xor(p3, 32);
      float a = (lane & 32) ? p1 : p0;
      float b = (lane & 32) ? p3 : p2;
      a += __shfl_xor(a, 16); b += __shfl_xor(b, 16);
      float cpk = (lane & 16) ? b : a;
      cpk += __shfl_xor(cpk, 8); cpk += __shfl_xor(cpk, 4);
      cpk += __shfl_xor(cpk, 2); cpk += __shfl_xor(cpk, 1);
      // lanes 0-15:P0, 16-31:P2, 32-47:P1, 48-63:P3
      float w = __expf(cpk);
      float w0 = __shfl(w, 0),  w2 = __shfl(w, 16);
      float w1 = __shfl(w, 32), w3 = __shfl(w, 48);
      s0 += w0 + w2; s1 += w1 + w3;
#pragma unroll
      for (int v = 0; v < VPL; v++) {
        acc0[v] += w0 * x0[v] + w2 * x2[v];
        acc1[v] += w1 * x1[v] + w3 * x3[v];
      }
    }
    for (; e < e1; ++e) {
      RawT r0 = *(const RawT*)(xl + (size_t)esrc[e] * C + base);
      float x0[VPL];
      cvt(r0, x0);
      float p0 = score(x0);
#pragma unroll
      for (int d2 = 32; d2; d2 >>= 1) p0 += __shfl_xor(p0, d2);
      float w0 = __expf(p0);
      s0 += w0;
#pragma unroll
      for (int v = 0; v < VPL; v++) acc0[v] += w0 * x0[v];
    }
    float inv = 1.f / (s0 + s1 + 1e-16f);
#pragma unroll
    for (int v = 0; v < VPL; v++) {
      float o = (acc0[v] + acc1[v]) * inv + bias[base + v];
      if (do_relu) o = fmaxf(o, 0.f);
      if constexpr (sizeof(OutT) == 2) out[(size_t)node * C + base + v] = f2bf(o);
      else out[(size_t)node * C + base + v] = o;
    }
  }
}

// ---------------- BN stats from bf16 h1 ---------------------------------------
__global__ __launch_bounds__(256) void bn_stats_kernel(
    const unsigned short* __restrict__ h1, float* __restrict__ stats, int n) {
  int tid = threadIdx.x;
  int c0 = tid * 2;
  int r0 = blockIdx.x * 64;
  int r1 = r0 + 64 < n ? r0 + 64 : n;
  float s0 = 0, q0 = 0, s1 = 0, q1 = 0;
  for (int r = r0; r < r1; ++r) {
    unsigned u = *(const unsigned*)&h1[(size_t)r * 512 + c0];
    float a = __uint_as_float(u << 16);
    float b = __uint_as_float(u & 0xffff0000u);
    s0 += a; q0 += a * a; s1 += b; q1 += b * b;
  }
  atomicAdd(&stats[c0], s0);
  atomicAdd(&stats[c0 + 1], s1);
  atomicAdd(&stats[512 + c0], q0);
  atomicAdd(&stats[512 + c0 + 1], q1);
}

// ---------------- launch ----------------
extern "C" void kernel_launch(void* const* d_in, const int* in_sizes, int n_in,
                              void* d_out, int out_size, void* d_ws, size_t ws_size,
                              hipStream_t stream) {
  (void)in_sizes; (void)n_in; (void)out_size; (void)ws_size;
  const float* x      = (const float*)d_in[0];
  const int*   ei     = (const int*)d_in[1];
  const float* conv_w = (const float*)d_in[2];
  const float* conv_b = (const float*)d_in[3];
  const float* W1l    = (const float*)d_in[4];
  const float* b1l    = (const float*)d_in[5];
  const float* W1r    = (const float*)d_in[6];
  const float* b1r    = (const float*)d_in[7];
  const float* att1   = (const float*)d_in[8];
  const float* bias1  = (const float*)d_in[9];
  const float* gamma  = (const float*)d_in[10];
  const float* beta   = (const float*)d_in[11];
  const float* W2l    = (const float*)d_in[12];
  const float* b2l    = (const float*)d_in[13];
  const float* W2r    = (const float*)d_in[14];
  const float* b2r    = (const float*)d_in[15];
  const float* att2   = (const float*)d_in[16];
  const float* bias2  = (const float*)d_in[17];

  char* ws = (char*)d_ws;
  size_t off = 0;
  auto alloc = [&](size_t bytes) {
    size_t r = off;
    off += (bytes + 255) & ~(size_t)255;
    return r;
  };
  size_t o_xb   = alloc((size_t)MPAD * 768 * 2);   // bf16 x (A of GEMM1)
  size_t o_wc1  = alloc((size_t)1024 * 768 * 2);   // Weff^T bf16
  size_t o_wc2  = alloc((size_t)256 * 512 * 2);    // W2eff^T bf16
  size_t o_xl1  = alloc((size_t)NN * 512 * 2);
  size_t o_xr1  = alloc((size_t)NN * 512 * 2);
  size_t o_h1   = alloc((size_t)MPAD * 512 * 2);   // bf16 relu(agg1)
  size_t o_xl2  = alloc((size_t)NN * 128 * 2);
  size_t o_xr2  = alloc((size_t)NN * 128 * 2);
  size_t o_off  = alloc((size_t)(NN + 1) * 4);
  size_t o_cur  = alloc((size_t)NN * 4);
  size_t o_deg  = alloc((size_t)NN * 4);
  size_t o_esrc = alloc((size_t)ETOT * 4);
  size_t o_stats = alloc((size_t)1024 * 4);
  size_t o_beff1 = alloc((size_t)1024 * 4);
  size_t o_beff2 = alloc((size_t)256 * 4);
  size_t o_btot  = alloc((size_t)64 * 4);
  size_t o_gbase = alloc((size_t)64 * 4);

  unsigned short* xb  = (unsigned short*)(ws + o_xb);
  unsigned short* wc1 = (unsigned short*)(ws + o_wc1);
  unsigned short* wc2 = (unsigned short*)(ws + o_wc2);
  unsigned short* xl1 = (unsigned short*)(ws + o_xl1);
  unsigned short* xr1 = (unsigned short*)(ws + o_xr1);
  unsigned short* h1  = (unsigned short*)(ws + o_h1);
  unsigned short* xl2 = (unsigned short*)(ws + o_xl2);
  unsigned short* xr2 = (unsigned short*)(ws + o_xr2);
  int* offp  = (int*)(ws + o_off);
  int* curp  = (int*)(ws + o_cur);
  int* degp  = (int*)(ws + o_deg);
  int* esrc  = (int*)(ws + o_esrc);
  float* stats = (float*)(ws + o_stats);
  float* beff1 = (float*)(ws + o_beff1);
  float* beff2 = (float*)(ws + o_beff2);
  int* btot  = (int*)(ws + o_btot);
  int* gbase = (int*)(ws + o_gbase);

  const int* src_raw = ei;
  const int* dst_raw = ei + ERAW;
  float* mu = (float*)d_out;

  cast_x_kernel<<<(MPAD * 96) / 256, 256, 0, stream>>>(x, xb, degp, stats, beff1);
  weff_kernel<<<dim3(32, 8), 256, 0, stream>>>(conv_w, conv_b, W1l, b1l, W1r, b1r, wc1, beff1);

  hist_kernel<<<(ERAW + 255) / 256, 256, 0, stream>>>(dst_raw, degp, ERAW);
  const int NB = (NN + 1023) / 1024;  // 20
  scan1_kernel<<<NB, 1024, 0, stream>>>(degp, offp, btot, NN);
  scan2_kernel<<<1, 64, 0, stream>>>(btot, gbase, offp, NB, NN);
  scan3_kernel<<<NB, 1024, 0, stream>>>(offp, curp, gbase, esrc, NN);
  scatter_kernel<<<(ERAW + 255) / 256, 256, 0, stream>>>(src_raw, dst_raw, curp, esrc, ERAW);

  // layer 1: xl1/xr1 = xb @ Weff + beff1   (conv folded in; K=768)
  gemm_kernel<unsigned short><<<(MPAD / 128) * (1024 / 128), 256, 0, stream>>>(
      xb, wc1, beff1, beff1 + 512, xl1, xr1, NN, 768, 8, 512, 1);
  // 1024 fully-resident blocks, per-wave grid-stride over MPAD node slots
  gat_agg_kernel<8, unsigned short><<<1024, 256, 0, stream>>>(
      xl1, xr1, att1, bias1, offp, esrc, h1, MPAD, NN, 1);

  // batchnorm stats + fold into W2
  bn_stats_kernel<<<(NN + 63) / 64, 256, 0, stream>>>(h1, stats, NN);
  w2fold_kernel<<<256, 256, 0, stream>>>(stats, gamma, beta, W2l, b2l, W2r, b2r, wc2, beff2);

  // layer 2: xl2/xr2 = h1 @ W2eff + beff2  (BN folded in; K=512)
  gemm_kernel<unsigned short><<<(MPAD / 128) * (256 / 128), 256, 0, stream>>>(
      h1, wc2, beff2, beff2 + 128, xl2, xr2, NN, 512, 2, 128, 0);
  gat_agg_kernel<2, float><<<1024, 256, 0, stream>>>(
      xl2, xr2, att2, bias2, offp, esrc, mu, NN, NN, 0);
}

// Round 13
// 266.684 us; speedup vs baseline: 1.0403x; 1.0403x over previous
//
#include <hip/hip_runtime.h>
#include <cstdint>
#include <cstddef>
#include <type_traits>

static constexpr int NN   = 20000;     // nodes
static constexpr int MPAD = 20096;     // 157 * 128
static constexpr int ERAW = 320000;    // given edges
static constexpr int ETOT = ERAW + NN; // + self loops

typedef __attribute__((ext_vector_type(8))) short bf16x8;
typedef __attribute__((ext_vector_type(8))) unsigned short u16x8;
typedef __attribute__((ext_vector_type(4))) float f32x4;

__device__ __forceinline__ unsigned short f2bf(float f) {
  union { float f; unsigned u; } v; v.f = f;
  unsigned r = v.u + 0x7fffu + ((v.u >> 16) & 1u);
  return (unsigned short)(r >> 16);
}
__device__ __forceinline__ float bf2f(unsigned short u) {
  union { unsigned u; float f; } v; v.u = ((unsigned)u) << 16;
  return v.f;
}

__device__ __forceinline__ void gload_lds16(const void* g, void* l) {
  __builtin_amdgcn_global_load_lds(
      (const __attribute__((address_space(1))) unsigned int*)g,
      (__attribute__((address_space(3))) unsigned int*)l, 16, 0, 0);
}

// ---------------- x fp32 -> bf16 cast + zero-init (fused) ---------------------
__global__ __launch_bounds__(256) void cast_x_kernel(
    const float* __restrict__ x, unsigned short* __restrict__ xb,
    int* __restrict__ degp, float* __restrict__ stats, float* __restrict__ beff1) {
  int i8 = blockIdx.x * 256 + threadIdx.x;   // 8-elem chunk; 96 chunks/row
  if (i8 < NN) degp[i8] = 0;
  if (i8 < 1024) { stats[i8] = 0.f; beff1[i8] = 0.f; }
  size_t base = (size_t)i8 * 8;
  int row = i8 / 96;
  u16x8 o;
  if (row < NN) {
    float4 a = *(const float4*)&x[base];
    float4 b = *(const float4*)&x[base + 4];
    o[0] = f2bf(a.x); o[1] = f2bf(a.y); o[2] = f2bf(a.z); o[3] = f2bf(a.w);
    o[4] = f2bf(b.x); o[5] = f2bf(b.y); o[6] = f2bf(b.z); o[7] = f2bf(b.w);
  } else {
#pragma unroll
    for (int j = 0; j < 8; j++) o[j] = 0;
  }
  *(u16x8*)&xb[base] = o;
}

// ---------------- conv folded into W1: Weff^T[c][k*32+t], beff1[c] ------------
// grid (32 t, 8 c-chunks); thread pair (c, half) splits the o-loop 32/32.
__global__ __launch_bounds__(256) void weff_kernel(
    const float* __restrict__ conv_w, const float* __restrict__ conv_b,
    const float* __restrict__ W1l, const float* __restrict__ b1l,
    const float* __restrict__ W1r, const float* __restrict__ b1r,
    unsigned short* __restrict__ wc1, float* __restrict__ beff1) {
  __shared__ float ws[64 * 24];
  int t = blockIdx.x;                 // 0..31
  int tid = threadIdx.x;
  for (int i = tid; i < 64 * 24; i += 256) ws[i] = conv_w[i];
  __syncthreads();
  int c = blockIdx.y * 128 + (tid >> 1);   // 0..1023
  int half = tid & 1;
  const float* W; const float* bb; int cl;
  if (c < 512) { W = W1l; bb = b1l; cl = c; } else { W = W1r; bb = b1r; cl = c - 512; }
  float acc[24];
#pragma unroll
  for (int k = 0; k < 24; k++) acc[k] = 0.f;
  float bacc = (t == 0 && half == 0) ? bb[cl] : 0.f;
  for (int o = half * 32; o < half * 32 + 32; o += 4) {
    float Wv[4];
#pragma unroll
    for (int j = 0; j < 4; j++) Wv[j] = W[(size_t)((o + j) * 32 + t) * 512 + cl];
#pragma unroll
    for (int j = 0; j < 4; j++) {
      bacc += conv_b[o + j] * Wv[j];
#pragma unroll
      for (int k = 0; k < 24; k++) acc[k] += ws[(o + j) * 24 + k] * Wv[j];
    }
  }
#pragma unroll
  for (int k = 0; k < 24; k++) acc[k] += __shfl_xor(acc[k], 1);
  bacc += __shfl_xor(bacc, 1);
  if (half == 0) {
#pragma unroll
    for (int k = 0; k < 24; k++) wc1[(size_t)c * 768 + k * 32 + t] = f2bf(acc[k]);
    atomicAdd(&beff1[c], bacc);
  }
}

// ---------------- BN folded into W2 (parallel; sc/sh computed inline) ---------
__global__ __launch_bounds__(256) void w2fold_kernel(
    const float* __restrict__ stats, const float* __restrict__ gamma,
    const float* __restrict__ beta,
    const float* __restrict__ W2l, const float* __restrict__ b2l,
    const float* __restrict__ W2r, const float* __restrict__ b2r,
    unsigned short* __restrict__ wc2, float* __restrict__ beff2) {
  int c = blockIdx.x;                 // 0..255
  const float* W; const float* bb; int cl;
  if (c < 128) { W = W2l; bb = b2l; cl = c; } else { W = W2r; bb = b2r; cl = c - 128; }
  int tid = threadIdx.x, lane = tid & 63, wid = tid >> 6;
  float part = 0.f;
#pragma unroll
  for (int j = 0; j < 2; j++) {
    int k = tid * 2 + j;
    float mean = stats[k] * (1.f / NN);
    float var = stats[512 + k] * (1.f / NN) - mean * mean;
    float rstd = rsqrtf(var + 1e-5f);
    float sc = gamma[k] * rstd;
    float sh = beta[k] - sc * mean;
    float wv = W[(size_t)k * 128 + cl];
    wc2[(size_t)c * 512 + k] = f2bf(sc * wv);
    part += sh * wv;
  }
#pragma unroll
  for (int d = 32; d; d >>= 1) part += __shfl_xor(part, d);
  __shared__ float wsum[4];
  if (lane == 0) wsum[wid] = part;
  __syncthreads();
  if (tid == 0) beff2[c] = bb[cl] + wsum[0] + wsum[1] + wsum[2] + wsum[3];
}

// ---------------- bf16 MFMA GEMM (m97 2-phase + T2 swizzle + T1) --------------
template <typename OutT>
__global__ __launch_bounds__(256, 5) void gemm_kernel(
    const unsigned short* __restrict__ A, const unsigned short* __restrict__ B,
    const float* __restrict__ bias0, const float* __restrict__ bias1,
    OutT* __restrict__ C0, OutT* __restrict__ C1,
    int M, int K, int NT, int nsplit, int swz) {
  __shared__ __align__(16) unsigned short As[128 * 64];
  __shared__ __align__(16) unsigned short Bs[128 * 64];
  int bid = blockIdx.x;
  if (swz) bid = (bid & 7) * (gridDim.x >> 3) + (bid >> 3);  // XCD-chunked (nwg%8==0)
  int tm = bid / NT, tn = bid % NT;
  int tid = threadIdx.x, wid = tid >> 6, lane = tid & 63;
  int wr = wid >> 1, wc = wid & 1;
  const unsigned short* gA = A + (size_t)(tm * 128) * K;
  const unsigned short* gB = B + (size_t)(tn * 128) * K;
  int srow = wid * 8 + (lane >> 3);
  int scol = ((lane & 7) ^ (lane >> 3)) * 8;   // T2: srow&7 == lane>>3

  f32x4 acc[4][4];
  f32x4 zero = {0.f, 0.f, 0.f, 0.f};
#pragma unroll
  for (int i = 0; i < 4; i++)
#pragma unroll
    for (int j = 0; j < 4; j++) acc[i][j] = zero;

  int KT = K >> 6;
  for (int kt = 0; kt < KT; ++kt) {
    if (kt) __syncthreads();
    {
      const unsigned short* a0 = gA + (size_t)srow * K + kt * 64 + scol;
      const unsigned short* b0 = gB + (size_t)srow * K + kt * 64 + scol;
#pragma unroll
      for (int i = 0; i < 4; i++)
        gload_lds16(a0 + (size_t)i * 32 * K, &As[i * 2048 + wid * 512]);
#pragma unroll
      for (int i = 0; i < 4; i++)
        gload_lds16(b0 + (size_t)i * 32 * K, &Bs[i * 2048 + wid * 512]);
    }
    asm volatile("s_waitcnt vmcnt(0)" ::: "memory");
    __syncthreads();
#pragma unroll
    for (int kk = 0; kk < 2; kk++) {
      int ko = kk * 32 + (lane >> 4) * 8;
      int kosw = ko ^ ((lane & 7) << 3);       // T2 read: r&7 == lane&7
      bf16x8 af[4], bfr[4];
#pragma unroll
      for (int mi = 0; mi < 4; mi++)
        af[mi] = *(const bf16x8*)&As[(wr * 64 + mi * 16 + (lane & 15)) * 64 + kosw];
#pragma unroll
      for (int ni = 0; ni < 4; ni++)
        bfr[ni] = *(const bf16x8*)&Bs[(wc * 64 + ni * 16 + (lane & 15)) * 64 + kosw];
#pragma unroll
      for (int mi = 0; mi < 4; mi++)
#pragma unroll
        for (int ni = 0; ni < 4; ni++)
          acc[mi][ni] = __builtin_amdgcn_mfma_f32_16x16x32_bf16(
              af[mi], bfr[ni], acc[mi][ni], 0, 0, 0);
    }
  }

  int ncol_tile = tn * 128;
  OutT* Cd; const float* bs; int col0;
  if (ncol_tile < nsplit) { Cd = C0; bs = bias0; col0 = ncol_tile; }
  else { Cd = C1; bs = bias1; col0 = ncol_tile - nsplit; }
#pragma unroll
  for (int mi = 0; mi < 4; mi++) {
    int rbase = tm * 128 + wr * 64 + mi * 16 + (lane >> 4) * 4;
#pragma unroll
    for (int ni = 0; ni < 4; ni++) {
      int c = col0 + wc * 64 + ni * 16 + (lane & 15);
      float bv = bs[c];
#pragma unroll
      for (int j = 0; j < 4; j++) {
        int r = rbase + j;
        if (r < M) {
          float v = acc[mi][ni][j] + bv;
          if constexpr (sizeof(OutT) == 2) Cd[(size_t)r * nsplit + c] = f2bf(v);
          else Cd[(size_t)r * nsplit + c] = v;
        }
      }
    }
  }
}

// ---------------- CSR build (self-loop placed first per segment) --------------
__global__ void hist_kernel(const int* __restrict__ dst, int* deg, int E) {
  int e = blockIdx.x * 256 + threadIdx.x;
  if (e < E) atomicAdd(&deg[dst[e]], 1);
}
__global__ __launch_bounds__(1024) void scan1_kernel(
    const int* __restrict__ deg, int* __restrict__ off, int* __restrict__ btot, int n) {
  __shared__ int wsum[16];
  int tid = threadIdx.x, lane = tid & 63, w = tid >> 6;
  int i = blockIdx.x * 1024 + tid;
  int v = (i < n) ? deg[i] + 1 : 0;    // +1 self loop
  int s = v;
#pragma unroll
  for (int d = 1; d < 64; d <<= 1) {
    int t = __shfl_up(s, d);
    if (lane >= d) s += t;
  }
  if (lane == 63) wsum[w] = s;
  __syncthreads();
  if (w == 0 && lane < 16) {
    int t = wsum[lane];
#pragma unroll
    for (int d = 1; d < 16; d <<= 1) {
      int u = __shfl_up(t, d);
      if (lane >= d) t += u;
    }
    wsum[lane] = t;
  }
  __syncthreads();
  int incl = (w ? wsum[w - 1] : 0) + s;
  if (i < n) off[i] = incl - v;               // block-local exclusive
  if (tid == 1023) btot[blockIdx.x] = incl;
}
__global__ void scan2_kernel(const int* __restrict__ btot, int* __restrict__ gbase,
                             int* __restrict__ off, int nb, int n) {
  int lane = threadIdx.x;
  int v = lane < nb ? btot[lane] : 0;
  int s = v;
#pragma unroll
  for (int d = 1; d < 64; d <<= 1) {
    int t = __shfl_up(s, d);
    if (lane >= d) s += t;
  }
  if (lane < nb) gbase[lane] = s - v;
  if (lane == nb - 1) off[n] = s;
}
__global__ __launch_bounds__(1024) void scan3_kernel(
    int* __restrict__ off, int* __restrict__ cursor,
    const int* __restrict__ gbase, int* __restrict__ esrc, int n) {
  int i = blockIdx.x * 1024 + threadIdx.x;
  if (i < n) {
    int v = off[i] + gbase[blockIdx.x];
    off[i] = v;
    cursor[i] = v + 1;    // slot v reserved for self loop
    esrc[v] = i;
  }
}
__global__ void scatter_kernel(const int* __restrict__ src, const int* __restrict__ dst,
                               int* cursor, int* __restrict__ esrc, int E) {
  int e = blockIdx.x * 256 + threadIdx.x;
  if (e < E) {
    int pos = atomicAdd(&cursor[dst[e]], 1);
    esrc[pos] = src[e];
  }
}

// ---------------- GATv2 aggregate: wave/node, packed 4-way butterfly ----------
// Grid covers npad/4 nodes; nodes in [n, npad) write zero rows (pad for GEMM A).
template <int VPL, typename OutT>
__global__ __launch_bounds__(256) void gat_agg_kernel(
    const unsigned short* __restrict__ xl, const unsigned short* __restrict__ xr,
    const float* __restrict__ att, const float* __restrict__ bias,
    const int* __restrict__ off, const int* __restrict__ esrc,
    OutT* __restrict__ out, int n, int do_relu) {
  constexpr int C = VPL * 64;
  using RawT = std::conditional_t<VPL == 8, uint4, unsigned int>;
  int node = blockIdx.x * 4 + (threadIdx.x >> 6);
  int lane = threadIdx.x & 63;
  int base = lane * VPL;
  if (node >= n) {
#pragma unroll
    for (int v = 0; v < VPL; v++) out[(size_t)node * C + base + v] = OutT(0);
    return;
  }
  float xrv[VPL], attv[VPL];
#pragma unroll
  for (int v = 0; v < VPL; v++) {
    xrv[v] = bf2f(xr[(size_t)node * C + base + v]);
    attv[v] = att[base + v];
  }
  auto cvt = [](RawT r, float* xv) {
    if constexpr (VPL == 8) {
      unsigned u[4] = {r.x, r.y, r.z, r.w};
#pragma unroll
      for (int i = 0; i < 4; i++) {
        xv[2 * i]     = __uint_as_float(u[i] << 16);
        xv[2 * i + 1] = __uint_as_float(u[i] & 0xffff0000u);
      }
    } else {
      xv[0] = __uint_as_float(r << 16);
      xv[1] = __uint_as_float(r & 0xffff0000u);
    }
  };
  auto score = [&](const float* xv) {
    float p = 0.f;
#pragma unroll
    for (int v = 0; v < VPL; v++) {
      float t = xv[v] + xrv[v];
      p += attv[v] * fmaxf(t, 0.2f * t);   // leaky_relu(0.2) = max(t, 0.2t)
    }
    return p;
  };
  float s0 = 0.f, s1 = 0.f;
  float acc0[VPL], acc1[VPL];
#pragma unroll
  for (int v = 0; v < VPL; v++) { acc0[v] = 0.f; acc1[v] = 0.f; }
  int e0 = off[node], e1 = off[node + 1];
  int e = e0;
  for (; e + 3 < e1; e += 4) {
    int s0i = esrc[e], s1i = esrc[e + 1], s2i = esrc[e + 2], s3i = esrc[e + 3];
    RawT r0 = *(const RawT*)(xl + (size_t)s0i * C + base);
    RawT r1 = *(const RawT*)(xl + (size_t)s1i * C + base);
    RawT r2 = *(const RawT*)(xl + (size_t)s2i * C + base);
    RawT r3 = *(const RawT*)(xl + (size_t)s3i * C + base);
    float x0[VPL], x1[VPL], x2[VPL], x3[VPL];
    cvt(r0, x0); cvt(r1, x1); cvt(r2, x2); cvt(r3, x3);
    float p0 = score(x0), p1 = score(x1), p2 = score(x2), p3 = score(x3);
    // packed 4-value butterfly: one tree instead of four.
    p0 += __shfl_xor(p0, 32); p1 += __shfl_xor(p1, 32);
    p2 += __shfl_xor(p2, 32); p3 += __shfl_xor(p3, 32);
    float a = (lane & 32) ? p1 : p0;
    float b = (lane & 32) ? p3 : p2;
    a += __shfl_xor(a, 16); b += __shfl_xor(b, 16);
    float cpk = (lane & 16) ? b : a;
    cpk += __shfl_xor(cpk, 8); cpk += __shfl_xor(cpk, 4);
    cpk += __shfl_xor(cpk, 2); cpk += __shfl_xor(cpk, 1);
    // lanes 0-15:P0, 16-31:P2, 32-47:P1, 48-63:P3
    float w = __expf(cpk);
    float w0 = __shfl(w, 0),  w2 = __shfl(w, 16);
    float w1 = __shfl(w, 32), w3 = __shfl(w, 48);
    s0 += w0 + w2; s1 += w1 + w3;
#pragma unroll
    for (int v = 0; v < VPL; v++) {
      acc0[v] += w0 * x0[v] + w2 * x2[v];
      acc1[v] += w1 * x1[v] + w3 * x3[v];
    }
  }
  for (; e < e1; ++e) {
    RawT r0 = *(const RawT*)(xl + (size_t)esrc[e] * C + base);
    float x0[VPL];
    cvt(r0, x0);
    float p0 = score(x0);
#pragma unroll
    for (int d2 = 32; d2; d2 >>= 1) p0 += __shfl_xor(p0, d2);
    float w0 = __expf(p0);
    s0 += w0;
#pragma unroll
    for (int v = 0; v < VPL; v++) acc0[v] += w0 * x0[v];
  }
  float inv = 1.f / (s0 + s1 + 1e-16f);
#pragma unroll
  for (int v = 0; v < VPL; v++) {
    float o = (acc0[v] + acc1[v]) * inv + bias[base + v];
    if (do_relu) o = fmaxf(o, 0.f);
    if constexpr (sizeof(OutT) == 2) out[(size_t)node * C + base + v] = f2bf(o);
    else out[(size_t)node * C + base + v] = o;
  }
}

// ---------------- BN stats from bf16 h1 ---------------------------------------
__global__ __launch_bounds__(256) void bn_stats_kernel(
    const unsigned short* __restrict__ h1, float* __restrict__ stats, int n) {
  int tid = threadIdx.x;
  int c0 = tid * 2;
  int r0 = blockIdx.x * 64;
  int r1 = r0 + 64 < n ? r0 + 64 : n;
  float s0 = 0, q0 = 0, s1 = 0, q1 = 0;
  for (int r = r0; r < r1; ++r) {
    unsigned u = *(const unsigned*)&h1[(size_t)r * 512 + c0];
    float a = __uint_as_float(u << 16);
    float b = __uint_as_float(u & 0xffff0000u);
    s0 += a; q0 += a * a; s1 += b; q1 += b * b;
  }
  atomicAdd(&stats[c0], s0);
  atomicAdd(&stats[c0 + 1], s1);
  atomicAdd(&stats[512 + c0], q0);
  atomicAdd(&stats[512 + c0 + 1], q1);
}

// ---------------- launch ----------------
extern "C" void kernel_launch(void* const* d_in, const int* in_sizes, int n_in,
                              void* d_out, int out_size, void* d_ws, size_t ws_size,
                              hipStream_t stream) {
  (void)in_sizes; (void)n_in; (void)out_size; (void)ws_size;
  const float* x      = (const float*)d_in[0];
  const int*   ei     = (const int*)d_in[1];
  const float* conv_w = (const float*)d_in[2];
  const float* conv_b = (const float*)d_in[3];
  const float* W1l    = (const float*)d_in[4];
  const float* b1l    = (const float*)d_in[5];
  const float* W1r    = (const float*)d_in[6];
  const float* b1r    = (const float*)d_in[7];
  const float* att1   = (const float*)d_in[8];
  const float* bias1  = (const float*)d_in[9];
  const float* gamma  = (const float*)d_in[10];
  const float* beta   = (const float*)d_in[11];
  const float* W2l    = (const float*)d_in[12];
  const float* b2l    = (const float*)d_in[13];
  const float* W2r    = (const float*)d_in[14];
  const float* b2r    = (const float*)d_in[15];
  const float* att2   = (const float*)d_in[16];
  const float* bias2  = (const float*)d_in[17];

  char* ws = (char*)d_ws;
  size_t off = 0;
  auto alloc = [&](size_t bytes) {
    size_t r = off;
    off += (bytes + 255) & ~(size_t)255;
    return r;
  };
  size_t o_xb   = alloc((size_t)MPAD * 768 * 2);   // bf16 x (A of GEMM1)
  size_t o_wc1  = alloc((size_t)1024 * 768 * 2);   // Weff^T bf16
  size_t o_wc2  = alloc((size_t)256 * 512 * 2);    // W2eff^T bf16
  size_t o_xl1  = alloc((size_t)NN * 512 * 2);
  size_t o_xr1  = alloc((size_t)NN * 512 * 2);
  size_t o_h1   = alloc((size_t)MPAD * 512 * 2);   // bf16 relu(agg1)
  size_t o_xl2  = alloc((size_t)NN * 128 * 2);
  size_t o_xr2  = alloc((size_t)NN * 128 * 2);
  size_t o_off  = alloc((size_t)(NN + 1) * 4);
  size_t o_cur  = alloc((size_t)NN * 4);
  size_t o_deg  = alloc((size_t)NN * 4);
  size_t o_esrc = alloc((size_t)ETOT * 4);
  size_t o_stats = alloc((size_t)1024 * 4);
  size_t o_beff1 = alloc((size_t)1024 * 4);
  size_t o_beff2 = alloc((size_t)256 * 4);
  size_t o_btot  = alloc((size_t)64 * 4);
  size_t o_gbase = alloc((size_t)64 * 4);

  unsigned short* xb  = (unsigned short*)(ws + o_xb);
  unsigned short* wc1 = (unsigned short*)(ws + o_wc1);
  unsigned short* wc2 = (unsigned short*)(ws + o_wc2);
  unsigned short* xl1 = (unsigned short*)(ws + o_xl1);
  unsigned short* xr1 = (unsigned short*)(ws + o_xr1);
  unsigned short* h1  = (unsigned short*)(ws + o_h1);
  unsigned short* xl2 = (unsigned short*)(ws + o_xl2);
  unsigned short* xr2 = (unsigned short*)(ws + o_xr2);
  int* offp  = (int*)(ws + o_off);
  int* curp  = (int*)(ws + o_cur);
  int* degp  = (int*)(ws + o_deg);
  int* esrc  = (int*)(ws + o_esrc);
  float* stats = (float*)(ws + o_stats);
  float* beff1 = (float*)(ws + o_beff1);
  float* beff2 = (float*)(ws + o_beff2);
  int* btot  = (int*)(ws + o_btot);
  int* gbase = (int*)(ws + o_gbase);

  const int* src_raw = ei;
  const int* dst_raw = ei + ERAW;
  float* mu = (float*)d_out;

  cast_x_kernel<<<(MPAD * 96) / 256, 256, 0, stream>>>(x, xb, degp, stats, beff1);
  weff_kernel<<<dim3(32, 8), 256, 0, stream>>>(conv_w, conv_b, W1l, b1l, W1r, b1r, wc1, beff1);

  hist_kernel<<<(ERAW + 255) / 256, 256, 0, stream>>>(dst_raw, degp, ERAW);
  const int NB = (NN + 1023) / 1024;  // 20
  scan1_kernel<<<NB, 1024, 0, stream>>>(degp, offp, btot, NN);
  scan2_kernel<<<1, 64, 0, stream>>>(btot, gbase, offp, NB, NN);
  scan3_kernel<<<NB, 1024, 0, stream>>>(offp, curp, gbase, esrc, NN);
  scatter_kernel<<<(ERAW + 255) / 256, 256, 0, stream>>>(src_raw, dst_raw, curp, esrc, ERAW);

  // layer 1: xl1/xr1 = xb @ Weff + beff1   (conv folded in; K=768)
  gemm_kernel<unsigned short><<<(MPAD / 128) * (1024 / 128), 256, 0, stream>>>(
      xb, wc1, beff1, beff1 + 512, xl1, xr1, NN, 768, 8, 512, 1);
  // grid covers MPAD rows: pad nodes write zero h1 rows (GEMM2 A pad)
  gat_agg_kernel<8, unsigned short><<<MPAD / 4, 256, 0, stream>>>(
      xl1, xr1, att1, bias1, offp, esrc, h1, NN, 1);

  // batchnorm stats + fold into W2
  bn_stats_kernel<<<(NN + 63) / 64, 256, 0, stream>>>(h1, stats, NN);
  w2fold_kernel<<<256, 256, 0, stream>>>(stats, gamma, beta, W2l, b2l, W2r, b2r, wc2, beff2);

  // layer 2: xl2/xr2 = h1 @ W2eff + beff2  (BN folded in; K=512)
  gemm_kernel<unsigned short><<<(MPAD / 128) * (256 / 128), 256, 0, stream>>>(
      h1, wc2, beff2, beff2 + 128, xl2, xr2, NN, 512, 2, 128, 0);
  gat_agg_kernel<2, float><<<NN / 4, 256, 0, stream>>>(
      xl2, xr2, att2, bias2, offp, esrc, mu, NN, 0);
}